// Round 6
// baseline (35721.490 us; speedup 1.0000x reference)
//
#include <hip/hip_runtime.h>

#define BATCH 1024
#define SEQ   1024
#define FDIM  36
#define HID   20
#define G3    60
#define CR    64          // rows per LDS gi chunk
#define NCHUNK (SEQ/CR)   // 16

typedef float v2f __attribute__((ext_vector_type(2)));

__device__ __forceinline__ float fast_sigmoid(float x){
    return __builtin_amdgcn_rcpf(1.0f + __expf(-x));
}
__device__ __forceinline__ float fast_tanh(float x){
    return fmaf(-2.0f, __builtin_amdgcn_rcpf(1.0f + __expf(2.0f*x)), 1.0f);
}

#define READLANE_F(v, u) __int_as_float(__builtin_amdgcn_readlane(__float_as_int(v), (u)))

// One block per batch element. 4 waves:
//  - wave (blockIdx%4): encoder GRU then decoder GRU (R3-proven gate-row-major form)
//  - other 3 waves: producers — embed/concat -> origin rows + gi = Wih1@x+bih1 into
//    a double-buffered LDS chunk (64 timesteps). __syncthreads pipelines the chunks.
// gi never touches HBM. Producers exit after the last barrier; consumer decodes alone.
__global__ __launch_bounds__(256, 4)
void gru_fused(const float* __restrict__ x,
               const int* __restrict__ oh,
               const float* __restrict__ e0, const float* __restrict__ e1,
               const float* __restrict__ e2, const float* __restrict__ e3,
               const float* __restrict__ Wih1g, const float* __restrict__ Whh1g,
               const float* __restrict__ bih1g, const float* __restrict__ bhh1g,
               const float* __restrict__ Wih2g, const float* __restrict__ Whh2g,
               const float* __restrict__ bih2g, const float* __restrict__ bhh2g,
               const float* __restrict__ Wfcg,  const float* __restrict__ bfcg,
               float* __restrict__ origin, float* __restrict__ out2)
{
    __shared__ __align__(16) float gbuf[2][CR][G3];  // gi chunks (double buffer)
    __shared__ __align__(16) float psh[3][64];       // producer broadcast scratch
    __shared__ __align__(16) float dsh[64];          // decoder x broadcast

    const int lane  = threadIdx.x & 63;
    const int wslot = threadIdx.x >> 6;
    const int b = __builtin_amdgcn_readfirstlane(blockIdx.x);
    const int encslot = b & 3;                       // spread enc waves across SIMDs
    const bool is_enc = (wslot == encslot);

    const int k  = lane < G3   ? lane : G3 - 1;
    const int kf = lane < FDIM ? lane : FDIM - 1;

    // ---------------- consumer (enc+dec) register state ----------------
    float whh1[HID], whh2[HID], wfc[HID];
    v2f wih2p[FDIM/2];
    float bh1 = 0.f, bi2 = 0.f, bh2 = 0.f, bf = 0.f;
    float hs[HID];
    float hv = 0.0f;
    if (is_enc) {
        #pragma unroll
        for (int u = 0; u < HID; u++) whh1[u] = Whh1g[k * HID + u];
        #pragma unroll
        for (int q = 0; q < FDIM/2; q++) wih2p[q] = ((const v2f*)(Wih2g + k * FDIM))[q];
        #pragma unroll
        for (int u = 0; u < HID; u++) whh2[u] = Whh2g[k * HID + u];
        #pragma unroll
        for (int u = 0; u < HID; u++) wfc[u] = Wfcg[kf * HID + u];
        bh1 = bhh1g[k];
        bi2 = bih2g[k]; bh2 = bhh2g[k];
        bf  = bfcg[kf];
        #pragma unroll
        for (int u = 0; u < HID; u++) hs[u] = 0.0f;
    }

    // ---------------- producer register state ----------------
    const int j = lane;
    const float* tbl; int ohc, eshift, sub;
    if (j < 16)      { tbl = e0; ohc = 0; eshift = 2; sub = j - 12; }
    else if (j < 20) { tbl = e1; ohc = 1; eshift = 2; sub = j - 16; }
    else if (j < 28) { tbl = e2; ohc = 2; eshift = 3; sub = j - 20; }
    else             { tbl = e3; ohc = 3; eshift = 3; sub = j - 28; }
    if (sub < 0) sub = 0;
    if (sub > 7) sub = 7;
    const bool from_x = (j < 12);
    const float* pa = from_x ? (x + j) : (tbl + sub);
    v2f w1p[FDIM/2]; float bi1 = 0.f;
    int p = 0;
    if (!is_enc) {
        p = (wslot < encslot) ? wslot : wslot - 1;   // 0..2
        #pragma unroll
        for (int q = 0; q < FDIM/2; q++) w1p[q] = ((const v2f*)(Wih1g + k * FDIM))[q];
        bi1 = bih1g[k];
    }

#define GATE_STEP(GIV) do {                                                  \
        float h0 = bh1, h1 = 0.f, h2 = 0.f, h3 = 0.f;                        \
        _Pragma("unroll")                                                    \
        for (int uu = 0; uu < HID; uu += 4) {                                \
            h0 = fmaf(whh1[uu + 0], hs[uu + 0], h0);                         \
            h1 = fmaf(whh1[uu + 1], hs[uu + 1], h1);                         \
            h2 = fmaf(whh1[uu + 2], hs[uu + 2], h2);                         \
            h3 = fmaf(whh1[uu + 3], hs[uu + 3], h3);                         \
        }                                                                    \
        float gh = (h0 + h1) + (h2 + h3);                                    \
        float v   = (GIV) + gh;                                              \
        float vz  = __shfl(v,    (lane + 20) & 63);                          \
        float in_ = __shfl((GIV),(lane + 40) & 63);                          \
        float hn  = __shfl(gh,   (lane + 40) & 63);                          \
        float r = fast_sigmoid(v);                                           \
        float z = fast_sigmoid(vz);                                          \
        float n = fast_tanh(fmaf(r, hn, in_));                               \
        hv = n + z * (hv - n);                                               \
        _Pragma("unroll")                                                    \
        for (int uu = 0; uu < HID; uu++) hs[uu] = READLANE_F(hv, uu);        \
    } while (0)

#define CONSUME_CHUNK(CB) do {                                               \
        const float* gp = &gbuf[CB][0][k];                                   \
        float ga = gp[0], gbv = gp[G3];                                      \
        _Pragma("unroll 1")                                                  \
        for (int i = 0; i < CR; i += 2) {                                    \
            float ge = ga, go = gbv;                                         \
            if (i < CR - 2) ga = gp[(i + 2) * G3];                           \
            GATE_STEP(ge);                                                   \
            if (i < CR - 2) gbv = gp[(i + 3) * G3];                          \
            GATE_STEP(go);                                                   \
        }                                                                    \
    } while (0)

    // ---------------- pipelined chunk loop (all 4 waves, 16 barriers) ----------------
    #pragma unroll 1
    for (int c = 0; c < NCHUNK; ++c) {
        if (!is_enc) {
            // fill gbuf[c&1] with chunk c (rows p, p+3, ... within the chunk)
            const int rbase = b * SEQ + c * CR;
            float* gdst = &gbuf[c & 1][0][0];
            #pragma unroll 1
            for (int half = 0; half < 2; ++half) {
                int rws[11]; int ohv[11];
                #pragma unroll
                for (int n = 0; n < 11; n++) {
                    int i = p + 3 * (half * 11 + n);
                    if (i > CR - 1) i = CR - 1;          // duplicate row 63: benign
                    rws[n] = i;
                    ohv[n] = oh[(rbase + i) * 4 + ohc];
                }
                float valv[11];
                #pragma unroll
                for (int n = 0; n < 11; n++) {
                    int R = rbase + rws[n];
                    int off = from_x ? (R * 12) : (ohv[n] << eshift);
                    valv[n] = pa[off];
                }
                const float4* xp4 = (const float4*)psh[p];
                #pragma unroll
                for (int n = 0; n < 11; n++) {
                    const int i = rws[n];
                    const size_t R = (size_t)(rbase + i);
                    psh[p][lane] = valv[n];              // same-wave DS order guarantees
                    if (lane < FDIM) origin[R * FDIM + lane] = valv[n];
                    v2f a0 = {bi1, 0.f}, a1 = {0.f, 0.f};
                    #pragma unroll
                    for (int q = 0; q < 9; q++) {
                        float4 xv4 = xp4[q];
                        v2f xlo = {xv4.x, xv4.y}, xhi = {xv4.z, xv4.w};
                        a0 = __builtin_elementwise_fma(w1p[2*q],     xlo, a0);
                        a1 = __builtin_elementwise_fma(w1p[2*q + 1], xhi, a1);
                    }
                    float g = (a0.x + a1.x) + (a0.y + a1.y);
                    if (lane < G3) gdst[i * G3 + lane] = g;
                }
            }
        } else if (c > 0) {
            CONSUME_CHUNK((c - 1) & 1);
        }
        __syncthreads();
    }
    if (!is_enc) return;          // producers done (after their 16th barrier)

    CONSUME_CHUNK((NCHUNK - 1) & 1);   // last chunk, no more barriers

    // ---------------- handoff ----------------
    float hvd = fast_tanh(hv);
    #pragma unroll
    for (int u = 0; u < HID; u++) hs[u] = READLANE_F(hvd, u);

    float* orow = out2 + ((size_t)b * SEQ + (SEQ - 1)) * FDIM;

    float xv;
    {
        float a0 = bf, a1 = 0.f, a2 = 0.f, a3 = 0.f;
        #pragma unroll
        for (int u = 0; u < HID; u += 4) {
            a0 = fmaf(wfc[u + 0], hs[u + 0], a0);
            a1 = fmaf(wfc[u + 1], hs[u + 1], a1);
            a2 = fmaf(wfc[u + 2], hs[u + 2], a2);
            a3 = fmaf(wfc[u + 3], hs[u + 3], a3);
        }
        xv = fast_tanh((a0 + a1) + (a2 + a3));
    }
    dsh[lane] = xv;               // intra-wave broadcast (same wave, no barrier)
    if (lane < FDIM) orow[lane] = xv;

    // ---------------- decoder (gate-row major, R3-proven) ----------------
    const float4* xp4 = (const float4*)dsh;
    #pragma unroll 1
    for (int d = 1; d < SEQ; ++d) {
        orow -= FDIM;
        float4 xq[9];
        #pragma unroll
        for (int q = 0; q < 9; q++) xq[q] = xp4[q];
        float h0 = bh2, h1 = 0.f, h2 = 0.f, h3 = 0.f;
        #pragma unroll
        for (int u = 0; u < HID; u += 4) {
            h0 = fmaf(whh2[u + 0], hs[u + 0], h0);
            h1 = fmaf(whh2[u + 1], hs[u + 1], h1);
            h2 = fmaf(whh2[u + 2], hs[u + 2], h2);
            h3 = fmaf(whh2[u + 3], hs[u + 3], h3);
        }
        float gh = (h0 + h1) + (h2 + h3);
        v2f accA = {bi2, 0.f}, accB = {0.f, 0.f};
        #pragma unroll
        for (int q = 0; q < 9; q++) {
            v2f xlo = {xq[q].x, xq[q].y}, xhi = {xq[q].z, xq[q].w};
            accA = __builtin_elementwise_fma(wih2p[2*q],     xlo, accA);
            accB = __builtin_elementwise_fma(wih2p[2*q + 1], xhi, accB);
        }
        float gi = (accA.x + accB.x) + (accA.y + accB.y);
        float v   = gi + gh;
        float vz  = __shfl(v,  (lane + 20) & 63);
        float in_ = __shfl(gi, (lane + 40) & 63);
        float hn  = __shfl(gh, (lane + 40) & 63);
        float r = fast_sigmoid(v);
        float z = fast_sigmoid(vz);
        float n = fast_tanh(fmaf(r, hn, in_));
        float hraw = n + z * (hvd - n);
        hvd = fast_tanh(hraw);
        #pragma unroll
        for (int u = 0; u < HID; u++) hs[u] = READLANE_F(hvd, u);
        float a0 = bf, a1 = 0.f, a2 = 0.f, a3 = 0.f;
        #pragma unroll
        for (int u = 0; u < HID; u += 4) {
            a0 = fmaf(wfc[u + 0], hs[u + 0], a0);
            a1 = fmaf(wfc[u + 1], hs[u + 1], a1);
            a2 = fmaf(wfc[u + 2], hs[u + 2], a2);
            a3 = fmaf(wfc[u + 3], hs[u + 3], a3);
        }
        xv = fast_tanh((a0 + a1) + (a2 + a3));
        dsh[lane] = xv;           // issue LDS write before the global store
        if (lane < FDIM) orow[lane] = xv;
    }
}

extern "C" void kernel_launch(void* const* d_in, const int* in_sizes, int n_in,
                              void* d_out, int out_size, void* d_ws, size_t ws_size,
                              hipStream_t stream) {
    const float* x    = (const float*)d_in[0];
    const int*   oh   = (const int*)d_in[1];
    const float* e0   = (const float*)d_in[2];
    const float* e1   = (const float*)d_in[3];
    const float* e2   = (const float*)d_in[4];
    const float* e3   = (const float*)d_in[5];
    const float* Wih1 = (const float*)d_in[6];
    const float* Whh1 = (const float*)d_in[7];
    const float* bih1 = (const float*)d_in[8];
    const float* bhh1 = (const float*)d_in[9];
    const float* Wih2 = (const float*)d_in[10];
    const float* Whh2 = (const float*)d_in[11];
    const float* bih2 = (const float*)d_in[12];
    const float* bhh2 = (const float*)d_in[13];
    const float* Wfc  = (const float*)d_in[14];
    const float* bfc  = (const float*)d_in[15];

    float* out    = (float*)d_out;
    float* origin = out;                                // output 0: (B,S,F)
    float* out2   = out + (size_t)BATCH * SEQ * FDIM;   // output 1: (B,S,F)

    gru_fused<<<BATCH, 256, 0, stream>>>(x, oh, e0, e1, e2, e3,
                                         Wih1, Whh1, bih1, bhh1,
                                         Wih2, Whh2, bih2, bhh2,
                                         Wfc, bfc, origin, out2);
}

// Round 7
// 988.916 us; speedup vs baseline: 36.1219x; 36.1219x over previous
//
#include <hip/hip_runtime.h>

#define BATCH 1024
#define SEQ   1024
#define FDIM  36
#define HID   20
#define G3    60
#define CR    64          // rows per LDS gi chunk
#define NCHUNK (SEQ/CR)   // 16

typedef float v2f __attribute__((ext_vector_type(2)));

__device__ __forceinline__ float fast_sigmoid(float x){
    return __builtin_amdgcn_rcpf(1.0f + __expf(-x));
}
__device__ __forceinline__ float fast_tanh(float x){
    return fmaf(-2.0f, __builtin_amdgcn_rcpf(1.0f + __expf(2.0f*x)), 1.0f);
}

#define READLANE_F(v, u) __int_as_float(__builtin_amdgcn_readlane(__float_as_int(v), (u)))

// One block per batch element, 2 waves:
//  wave0 (consumer): encoder GRU then decoder GRU (R3-proven gate-row-major form)
//  wave1 (producer): embed/concat -> origin rows + gi = Wih1@x+bih1 into a
//                    double-buffered LDS chunk (64 steps). __syncthreads pipelines.
// gi never touches HBM. Producer has ~3x slack vs consumer.
// Register discipline (R6 lesson): decoder weights are loaded AFTER the chunk loop
// (live range must not span it), producer pipelines only 8 rows at a time.
// __launch_bounds__(128,2): 256-VGPR cap -> no scratch spill.
__global__ __launch_bounds__(128, 2)
void gru_fused(const float* __restrict__ x,
               const int* __restrict__ oh,
               const float* __restrict__ e0, const float* __restrict__ e1,
               const float* __restrict__ e2, const float* __restrict__ e3,
               const float* __restrict__ Wih1g, const float* __restrict__ Whh1g,
               const float* __restrict__ bih1g, const float* __restrict__ bhh1g,
               const float* __restrict__ Wih2g, const float* __restrict__ Whh2g,
               const float* __restrict__ bih2g, const float* __restrict__ bhh2g,
               const float* __restrict__ Wfcg,  const float* __restrict__ bfcg,
               float* __restrict__ origin, float* __restrict__ out2)
{
    __shared__ __align__(16) float gbuf[2][CR][G3];  // 30 KB gi double buffer
    __shared__ __align__(16) float psh[64];          // producer broadcast scratch
    __shared__ __align__(16) float dsh[64];          // decoder x broadcast

    const int lane   = threadIdx.x & 63;
    const bool is_enc = (threadIdx.x < 64);          // wave0 = consumer
    const int b = __builtin_amdgcn_readfirstlane(blockIdx.x);

    const int k = lane < G3 ? lane : G3 - 1;

    // ---- consumer cross-loop state (kept minimal: whh1 + hs only) ----
    float whh1[HID];
    float bh1 = 0.f;
    float hs[HID];
    float hv = 0.0f;
    if (is_enc) {
        #pragma unroll
        for (int u = 0; u < HID; u++) whh1[u] = Whh1g[k * HID + u];
        bh1 = bhh1g[k];
        #pragma unroll
        for (int u = 0; u < HID; u++) hs[u] = 0.0f;
    }

    // ---- producer state ----
    const int j = lane;
    const float* tbl; int ohc, eshift, sub;
    if (j < 16)      { tbl = e0; ohc = 0; eshift = 2; sub = j - 12; }
    else if (j < 20) { tbl = e1; ohc = 1; eshift = 2; sub = j - 16; }
    else if (j < 28) { tbl = e2; ohc = 2; eshift = 3; sub = j - 20; }
    else             { tbl = e3; ohc = 3; eshift = 3; sub = j - 28; }
    if (sub < 0) sub = 0;
    if (sub > 7) sub = 7;
    const bool from_x = (j < 12);
    const float* pa = from_x ? (x + j) : (tbl + sub);
    v2f w1p[FDIM/2]; float bi1 = 0.f;
    if (!is_enc) {
        #pragma unroll
        for (int q = 0; q < FDIM/2; q++) w1p[q] = ((const v2f*)(Wih1g + k * FDIM))[q];
        bi1 = bih1g[k];
    }

#define GATE_STEP(GIV, WHH, BH, HVAR) do {                                   \
        float h0 = BH, h1 = 0.f, h2 = 0.f, h3 = 0.f;                         \
        _Pragma("unroll")                                                    \
        for (int uu = 0; uu < HID; uu += 4) {                                \
            h0 = fmaf(WHH[uu + 0], hs[uu + 0], h0);                          \
            h1 = fmaf(WHH[uu + 1], hs[uu + 1], h1);                          \
            h2 = fmaf(WHH[uu + 2], hs[uu + 2], h2);                          \
            h3 = fmaf(WHH[uu + 3], hs[uu + 3], h3);                          \
        }                                                                    \
        float gh = (h0 + h1) + (h2 + h3);                                    \
        float v   = (GIV) + gh;                                              \
        float vz  = __shfl(v,    (lane + 20) & 63);                          \
        float in_ = __shfl((GIV),(lane + 40) & 63);                          \
        float hn  = __shfl(gh,   (lane + 40) & 63);                          \
        float r = fast_sigmoid(v);                                           \
        float z = fast_sigmoid(vz);                                          \
        float n = fast_tanh(fmaf(r, hn, in_));                               \
        HVAR = n + z * (HVAR - n);                                           \
        _Pragma("unroll")                                                    \
        for (int uu = 0; uu < HID; uu++) hs[uu] = READLANE_F(HVAR, uu);      \
    } while (0)

#define CONSUME_CHUNK(CB) do {                                               \
        const float* gp = &gbuf[CB][0][k];                                   \
        float ga = gp[0], gbv = gp[G3];                                      \
        _Pragma("unroll 1")                                                  \
        for (int i = 0; i < CR; i += 2) {                                    \
            float ge = ga, go = gbv;                                         \
            if (i < CR - 2) ga = gp[(i + 2) * G3];                           \
            GATE_STEP(ge, whh1, bh1, hv);                                    \
            if (i < CR - 2) gbv = gp[(i + 3) * G3];                          \
            GATE_STEP(go, whh1, bh1, hv);                                    \
        }                                                                    \
    } while (0)

    // ---------------- pipelined chunk loop ----------------
    #pragma unroll 1
    for (int c = 0; c < NCHUNK; ++c) {
        if (!is_enc) {
            const int rbase = b * SEQ + c * CR;
            float* gdst = &gbuf[c & 1][0][0];
            const float4* xp4 = (const float4*)psh;
            #pragma unroll 1
            for (int g = 0; g < CR / 8; ++g) {
                int ohv[8];
                #pragma unroll
                for (int n = 0; n < 8; n++)
                    ohv[n] = oh[(rbase + 8 * g + n) * 4 + ohc];
                float valv[8];
                #pragma unroll
                for (int n = 0; n < 8; n++) {
                    int R = rbase + 8 * g + n;
                    int off = from_x ? (R * 12) : (ohv[n] << eshift);
                    valv[n] = pa[off];
                }
                #pragma unroll
                for (int n = 0; n < 8; n++) {
                    const int i = 8 * g + n;
                    const size_t R = (size_t)(rbase + i);
                    psh[lane] = valv[n];              // same-wave DS ordering
                    if (lane < FDIM) origin[R * FDIM + lane] = valv[n];
                    v2f a0 = {bi1, 0.f}, a1 = {0.f, 0.f};
                    #pragma unroll
                    for (int q = 0; q < 9; q++) {
                        float4 xv4 = xp4[q];
                        v2f xlo = {xv4.x, xv4.y}, xhi = {xv4.z, xv4.w};
                        a0 = __builtin_elementwise_fma(w1p[2*q],     xlo, a0);
                        a1 = __builtin_elementwise_fma(w1p[2*q + 1], xhi, a1);
                    }
                    float gg = (a0.x + a1.x) + (a0.y + a1.y);
                    if (lane < G3) gdst[i * G3 + lane] = gg;
                }
            }
        } else if (c > 0) {
            CONSUME_CHUNK((c - 1) & 1);
        }
        __syncthreads();
    }
    if (!is_enc) return;              // producer done (after its final barrier)

    CONSUME_CHUNK((NCHUNK - 1) & 1);  // last chunk; no further barriers

    // ---- decoder weights loaded only now (live range does not span chunk loop) ----
    const int kf = lane < FDIM ? lane : FDIM - 1;
    float whh2[HID], wfc[HID];
    v2f wih2p[FDIM/2];
    #pragma unroll
    for (int q = 0; q < FDIM/2; q++) wih2p[q] = ((const v2f*)(Wih2g + k * FDIM))[q];
    #pragma unroll
    for (int u = 0; u < HID; u++) whh2[u] = Whh2g[k * HID + u];
    #pragma unroll
    for (int u = 0; u < HID; u++) wfc[u] = Wfcg[kf * HID + u];
    const float bi2 = bih2g[k], bh2 = bhh2g[k];
    const float bf  = bfcg[kf];

    // ---------------- handoff ----------------
    float hvd = fast_tanh(hv);
    #pragma unroll
    for (int u = 0; u < HID; u++) hs[u] = READLANE_F(hvd, u);

    float* orow = out2 + ((size_t)b * SEQ + (SEQ - 1)) * FDIM;

    float xv;
    {
        float a0 = bf, a1 = 0.f, a2 = 0.f, a3 = 0.f;
        #pragma unroll
        for (int u = 0; u < HID; u += 4) {
            a0 = fmaf(wfc[u + 0], hs[u + 0], a0);
            a1 = fmaf(wfc[u + 1], hs[u + 1], a1);
            a2 = fmaf(wfc[u + 2], hs[u + 2], a2);
            a3 = fmaf(wfc[u + 3], hs[u + 3], a3);
        }
        xv = fast_tanh((a0 + a1) + (a2 + a3));
    }
    dsh[lane] = xv;                   // intra-wave broadcast (same wave)
    if (lane < FDIM) orow[lane] = xv;

    // ---------------- decoder (gate-row major, R3-proven) ----------------
    const v2f* xp = (const v2f*)dsh;
    #pragma unroll 1
    for (int d = 1; d < SEQ; ++d) {
        orow -= FDIM;
        v2f xs2[FDIM/2];
        #pragma unroll
        for (int q = 0; q < FDIM/2; q++) xs2[q] = xp[q];
        float h0 = bh2, h1 = 0.f, h2 = 0.f, h3 = 0.f;
        #pragma unroll
        for (int u = 0; u < HID; u += 4) {
            h0 = fmaf(whh2[u + 0], hs[u + 0], h0);
            h1 = fmaf(whh2[u + 1], hs[u + 1], h1);
            h2 = fmaf(whh2[u + 2], hs[u + 2], h2);
            h3 = fmaf(whh2[u + 3], hs[u + 3], h3);
        }
        float gh = (h0 + h1) + (h2 + h3);
        v2f accA = {bi2, 0.f}, accB = {0.f, 0.f};
        #pragma unroll
        for (int q = 0; q < FDIM/2; q += 2) {
            accA = __builtin_elementwise_fma(wih2p[q],     xs2[q],     accA);
            accB = __builtin_elementwise_fma(wih2p[q + 1], xs2[q + 1], accB);
        }
        float gi = (accA.x + accB.x) + (accA.y + accB.y);
        float v   = gi + gh;
        float vz  = __shfl(v,  (lane + 20) & 63);
        float in_ = __shfl(gi, (lane + 40) & 63);
        float hn  = __shfl(gh, (lane + 40) & 63);
        float r = fast_sigmoid(v);
        float z = fast_sigmoid(vz);
        float n = fast_tanh(fmaf(r, hn, in_));
        float hraw = n + z * (hvd - n);
        hvd = fast_tanh(hraw);
        #pragma unroll
        for (int u = 0; u < HID; u++) hs[u] = READLANE_F(hvd, u);
        float a0 = bf, a1 = 0.f, a2 = 0.f, a3 = 0.f;
        #pragma unroll
        for (int u = 0; u < HID; u += 4) {
            a0 = fmaf(wfc[u + 0], hs[u + 0], a0);
            a1 = fmaf(wfc[u + 1], hs[u + 1], a1);
            a2 = fmaf(wfc[u + 2], hs[u + 2], a2);
            a3 = fmaf(wfc[u + 3], hs[u + 3], a3);
        }
        xv = fast_tanh((a0 + a1) + (a2 + a3));
        dsh[lane] = xv;               // LDS write issued before the global store
        if (lane < FDIM) orow[lane] = xv;
    }
}

extern "C" void kernel_launch(void* const* d_in, const int* in_sizes, int n_in,
                              void* d_out, int out_size, void* d_ws, size_t ws_size,
                              hipStream_t stream) {
    const float* x    = (const float*)d_in[0];
    const int*   oh   = (const int*)d_in[1];
    const float* e0   = (const float*)d_in[2];
    const float* e1   = (const float*)d_in[3];
    const float* e2   = (const float*)d_in[4];
    const float* e3   = (const float*)d_in[5];
    const float* Wih1 = (const float*)d_in[6];
    const float* Whh1 = (const float*)d_in[7];
    const float* bih1 = (const float*)d_in[8];
    const float* bhh1 = (const float*)d_in[9];
    const float* Wih2 = (const float*)d_in[10];
    const float* Whh2 = (const float*)d_in[11];
    const float* bih2 = (const float*)d_in[12];
    const float* bhh2 = (const float*)d_in[13];
    const float* Wfc  = (const float*)d_in[14];
    const float* bfc  = (const float*)d_in[15];

    float* out    = (float*)d_out;
    float* origin = out;                                // output 0: (B,S,F)
    float* out2   = out + (size_t)BATCH * SEQ * FDIM;   // output 1: (B,S,F)

    gru_fused<<<BATCH, 128, 0, stream>>>(x, oh, e0, e1, e2, e3,
                                         Wih1, Whh1, bih1, bhh1,
                                         Wih2, Whh2, bih2, bhh2,
                                         Wfc, bfc, origin, out2);
}